// Round 7
// baseline (631.204 us; speedup 1.0000x reference)
//
#include <hip/hip_runtime.h>
#include <hip/hip_fp16.h>
#include <hip/hip_cooperative_groups.h>

namespace cg = cooperative_groups;

#define N_NODES 100000
#define N_EDGES 1600000
#define IN_DIM  165
#define HIDDEN  128
#define OUT_DIM 2

#define NBKT 196        // ceil(100000/512) buckets of 512 nodes
#define CHUNK 4096      // edges per partition block
#define NCHUNK ((N_EDGES + CHUNK - 1) / CHUNK)   // 391
#define PADCAP 10240    // arena/csr slots per bucket (mean 8163, sigma ~90)
#define KPAD 176        // 5*32 + 16
#define GROWS 64        // x rows staged per gemm1 tile
#define NTILE ((N_NODES + GROWS - 1) / GROWS)    // 1563

typedef _Float16 half8_t __attribute__((ext_vector_type(8)));
typedef _Float16 half4_t __attribute__((ext_vector_type(4)));
typedef float floatx4 __attribute__((ext_vector_type(4)));

// ================= shared phase implementations (used by mega + fallback) =============

template <int NT>
__device__ __forceinline__ void part2_chunk(int c, int t, int* hist, int* gbase,
        const int* __restrict__ src, const int* __restrict__ dst,
        int* __restrict__ bcnt, unsigned* __restrict__ arena) {
    int e0 = c * CHUNK;
    int nE = N_EDGES - e0; if (nE > CHUNK) nE = CHUNK;
    int n4 = nE >> 2;                       // N_EDGES % 4 == 0
    const int4* dst4 = (const int4*)(dst + e0);
    const int4* src4 = (const int4*)(src + e0);

    if (t < 256) hist[t] = 0;
    __syncthreads();
    for (int i = t; i < n4; i += NT) {
        int4 d = dst4[i];
        atomicAdd(&hist[d.x >> 9], 1);
        atomicAdd(&hist[d.y >> 9], 1);
        atomicAdd(&hist[d.z >> 9], 1);
        atomicAdd(&hist[d.w >> 9], 1);
    }
    __syncthreads();
    if (t < NBKT) gbase[t] = t * PADCAP + atomicAdd(&bcnt[t], hist[t]);
    if (t < 256) hist[t] = 0;   // reuse as rank counter
    __syncthreads();
    for (int i = t; i < n4; i += NT) {
        int4 d = dst4[i];
        int4 s = src4[i];
        #pragma unroll
        for (int j = 0; j < 4; j++) {
            int dd = (j == 0) ? d.x : (j == 1) ? d.y : (j == 2) ? d.z : d.w;
            int ss = (j == 0) ? s.x : (j == 1) ? s.y : (j == 2) ? s.z : s.w;
            int bk = dd >> 9;
            unsigned entry = (unsigned)ss | ((unsigned)(dd & 511) << 17);
            int idx = atomicAdd(&hist[bk], 1);
            arena[gbase[bk] + idx] = entry;
        }
    }
}

template <int NT>
__device__ __forceinline__ void sort4_bucket(int b, int t, int* cnt, int* cur, int* wsum,
        const unsigned* __restrict__ arena, const int* __restrict__ bcnt,
        int* __restrict__ csr, int* __restrict__ rowstart, int* __restrict__ rowend,
        float* __restrict__ dinv) {
    int n0 = b << 9;
    int lane = t & 63, wid = t >> 6;
    int total = bcnt[b];
    int abase = b * PADCAP;
    int dbase = b * PADCAP;        // csr padded layout
    int nt4 = total >> 2;
    const uint4* arena4 = (const uint4*)(arena + abase);

    for (int i = t; i < 512; i += NT) cnt[i] = 0;
    __syncthreads();
    for (int p = t; p < nt4; p += NT) {
        uint4 e = arena4[p];
        atomicAdd(&cnt[e.x >> 17], 1);
        atomicAdd(&cnt[e.y >> 17], 1);
        atomicAdd(&cnt[e.z >> 17], 1);
        atomicAdd(&cnt[e.w >> 17], 1);
    }
    {
        int p = (nt4 << 2) + t;
        if (p < total) atomicAdd(&cnt[arena[abase + p] >> 17], 1);
    }
    __syncthreads();

    // 512-entry exclusive scan by first 256 threads (thread t owns locals 2t, 2t+1)
    int c0 = 0, c1 = 0, s = 0, inc = 0;
    if (t < 256) {
        c0 = cnt[2 * t];
        c1 = cnt[2 * t + 1];
        s = c0 + c1;
        inc = s;
        #pragma unroll
        for (int off = 1; off < 64; off <<= 1) {
            int y = __shfl_up(inc, off);
            if (lane >= off) inc += y;
        }
        if (lane == 63) wsum[wid] = inc;
    }
    __syncthreads();
    if (t == 0) {
        int acc = 0;
        #pragma unroll
        for (int w = 0; w < 4; w++) { int tv = wsum[w]; wsum[w] = acc; acc += tv; }
    }
    __syncthreads();
    if (t < 256) {
        int base = dbase + wsum[wid] + (inc - s);
        cur[2 * t] = base;
        cur[2 * t + 1] = base + c0;
        int node0 = n0 + 2 * t;
        if (node0 < N_NODES) {
            rowstart[node0] = base;
            rowend[node0] = base + c0;
            dinv[node0] = rsqrtf((float)(c0 + 1));
        }
        if (node0 + 1 < N_NODES) {
            rowstart[node0 + 1] = base + c0;
            rowend[node0 + 1] = base + c0 + c1;
            dinv[node0 + 1] = rsqrtf((float)(c1 + 1));
        }
    }
    __syncthreads();

    for (int p = t; p < nt4; p += NT) {
        uint4 e = arena4[p];
        #pragma unroll
        for (int j = 0; j < 4; j++) {
            unsigned entry = (j == 0) ? e.x : (j == 1) ? e.y : (j == 2) ? e.z : e.w;
            int local = (int)(entry >> 17);
            int sv = (int)(entry & 0x1FFFFu);
            int pos = atomicAdd(&cur[local], 1);
            csr[pos] = sv;
        }
    }
    {
        int p = (nt4 << 2) + t;
        if (p < total) {
            unsigned entry = arena[abase + p];
            int local = (int)(entry >> 17);
            int sv = (int)(entry & 0x1FFFFu);
            int pos = atomicAdd(&cur[local], 1);
            csr[pos] = sv;
        }
    }
}

__device__ __forceinline__ void gemm1_tile(int tile, int t, float* xs,
        const float* __restrict__ x, const _Float16* __restrict__ w1t,
        const float* __restrict__ dinv, _Float16* __restrict__ h1s) {
    int wid = t >> 6, lane = t & 63;
    int row0 = tile * GROWS;
    int nrows = N_NODES - row0; if (nrows > GROWS) nrows = GROWS;   // tail 32, %16==0
    int nflt = nrows * IN_DIM;

    // coalesced stage: region [row0*165, +nflt) is contiguous; base 16B-aligned
    const float4* xb4 = (const float4*)(x + (size_t)row0 * IN_DIM);
    float4* xs4 = (float4*)xs;
    int n4 = nflt >> 2;
    for (int i = t; i < n4; i += 256) xs4[i] = xb4[i];
    for (int i = (n4 << 2) + t; i < nflt; i += 256) xs[i] = x[(size_t)row0 * IN_DIM + i];
    __syncthreads();

    int mrow = wid * 16;
    if (mrow >= nrows) return;              // all threads already passed the sync
    int m = lane & 15;
    int quad = lane >> 4;
    const float* xrow = xs + (mrow + m) * IN_DIM;
    int grow = row0 + mrow;

    floatx4 acc[8];
    #pragma unroll
    for (int i = 0; i < 8; i++) acc[i] = (floatx4)(0.f);

    #pragma unroll
    for (int kc = 0; kc < 5; kc++) {
        int kb = kc * 32 + quad * 8;       // max 152; +7 = 159 < 165
        half8_t a;
        #pragma unroll
        for (int j = 0; j < 8; j++) a[j] = (_Float16)xrow[kb + j];
        #pragma unroll
        for (int cb = 0; cb < 8; cb++) {
            int col = cb * 16 + m;
            half8_t bf = *(const half8_t*)&w1t[col * KPAD + kb];
            acc[cb] = __builtin_amdgcn_mfma_f32_16x16x32_f16(a, bf, acc[cb], 0, 0, 0);
        }
    }
    // K tail: 160..164 via 16x16x16 (k = quad*4 + j)
    {
        int kb = 160 + quad * 4;
        half4_t a;
        #pragma unroll
        for (int j = 0; j < 4; j++)
            a[j] = (kb + j < IN_DIM) ? (_Float16)xrow[kb + j] : (_Float16)0.f;
        #pragma unroll
        for (int cb = 0; cb < 8; cb++) {
            int col = cb * 16 + m;
            half4_t bf = *(const half4_t*)&w1t[col * KPAD + kb];
            acc[cb] = __builtin_amdgcn_mfma_f32_16x16x16f16(a, bf, acc[cb], 0, 0, 0);
        }
    }
    float dv[4];
    #pragma unroll
    for (int r = 0; r < 4; r++) dv[r] = dinv[grow + quad * 4 + r];
    #pragma unroll
    for (int cb = 0; cb < 8; cb++) {
        #pragma unroll
        for (int r = 0; r < 4; r++) {
            h1s[(size_t)(grow + quad * 4 + r) * HIDDEN + cb * 16 + m] =
                (_Float16)(acc[cb][r] * dv[r]);
        }
    }
}

__device__ __forceinline__ void agg1_node(int node, int lane,
        const _Float16* __restrict__ h1, const int* __restrict__ rowstart,
        const int* __restrict__ rowend, const int* __restrict__ csr,
        const float* __restrict__ dinv, const float* __restrict__ b1,
        const float* __restrict__ W2, float2* __restrict__ h2s) {
    int el = lane & 15;        // feature slot: owns features el*8 .. el*8+7
    int es = lane >> 4;        // edge slot 0..3

    float acc[8];
    {   // self term counted once (edge-slot 0)
        half8_t v = *(const half8_t*)(h1 + (size_t)node * HIDDEN + el * 8);
        #pragma unroll
        for (int j = 0; j < 8; j++) acc[j] = (es == 0) ? (float)v[j] : 0.f;
    }

    int p0 = rowstart[node], p1 = rowend[node];
    int p = p0 + es;
    for (; p + 4 < p1; p += 8) {        // 2-deep pipeline
        int sA = csr[p];
        int sB = csr[p + 4];
        half8_t vA = *(const half8_t*)(h1 + (size_t)sA * HIDDEN + el * 8);
        half8_t vB = *(const half8_t*)(h1 + (size_t)sB * HIDDEN + el * 8);
        #pragma unroll
        for (int j = 0; j < 8; j++) acc[j] += (float)vA[j];
        #pragma unroll
        for (int j = 0; j < 8; j++) acc[j] += (float)vB[j];
    }
    if (p < p1) {
        int s = csr[p];
        half8_t v = *(const half8_t*)(h1 + (size_t)s * HIDDEN + el * 8);
        #pragma unroll
        for (int j = 0; j < 8; j++) acc[j] += (float)v[j];
    }

    #pragma unroll
    for (int j = 0; j < 8; j++) {
        acc[j] += __shfl_xor(acc[j], 16);
        acc[j] += __shfl_xor(acc[j], 32);
    }

    float di = dinv[node];
    float4 bb0 = ((const float4*)b1)[el * 2];
    float4 bb1 = ((const float4*)b1)[el * 2 + 1];
    float bv[8] = {bb0.x, bb0.y, bb0.z, bb0.w, bb1.x, bb1.y, bb1.z, bb1.w};
    float a0 = 0.f, a1 = 0.f;
    #pragma unroll
    for (int j = 0; j < 8; j++) {
        float z = fmaf(di, acc[j], bv[j]);
        float r = fmaxf(z, 0.f);
        float2 w = ((const float2*)W2)[el * 8 + j];
        a0 = fmaf(r, w.x, a0);
        a1 = fmaf(r, w.y, a1);
    }
    #pragma unroll
    for (int off = 8; off; off >>= 1) {
        a0 += __shfl_xor(a0, off);
        a1 += __shfl_xor(a1, off);
    }
    if (lane == 0) h2s[node] = make_float2(di * a0, di * a1);
}

__device__ __forceinline__ void agg2_node(int node, int el,
        const float2* __restrict__ h2s, const int* __restrict__ rowstart,
        const int* __restrict__ rowend, const int* __restrict__ csr,
        const float* __restrict__ dinv, const float* __restrict__ b2,
        float2* __restrict__ out) {
    int p0 = rowstart[node], p1 = rowend[node];
    float ax = 0.f, ay = 0.f;
    for (int p = p0 + el; p < p1; p += 16) {
        float2 g = h2s[csr[p]];
        ax += g.x;
        ay += g.y;
    }
    #pragma unroll
    for (int off = 8; off; off >>= 1) {
        ax += __shfl_xor(ax, off);
        ay += __shfl_xor(ay, off);
    }
    if (el == 0) {
        float2 self = h2s[node];
        float di = dinv[node];
        out[node] = make_float2(fmaf(di, self.x + ax, b2[0]),
                                fmaf(di, self.y + ay, b2[1]));
    }
}

// ================= cooperative mega-kernel: whole pipeline, 1 dispatch ================

__global__ __launch_bounds__(256, 3) void k_mega(const float* __restrict__ x,
        const int* __restrict__ src, const int* __restrict__ dst,
        const float* __restrict__ W1, const float* __restrict__ b1,
        const float* __restrict__ W2, const float* __restrict__ b2,
        _Float16* __restrict__ h1s, float* __restrict__ dinv,
        int* __restrict__ rowstart, int* __restrict__ rowend,
        int* __restrict__ bcnt, unsigned* __restrict__ arena,
        int* __restrict__ csr, _Float16* __restrict__ w1t,
        float2* __restrict__ h2s, float2* __restrict__ outv) {
    cg::grid_group grid = cg::this_grid();
    __shared__ union {
        struct { int hist[256]; int gbase[256]; } p;
        struct { int cnt[512]; int cur[512]; int wsum[4]; } s;
        float xs[GROWS * IN_DIM];          // 42240 B -> 3 blocks/CU
    } sh;
    int bid = blockIdx.x, t = threadIdx.x, gn = gridDim.x;
    int lane = t & 63;

    // phase 0: W1 transpose + zero bcnt
    for (int idx = bid * 256 + t; idx < HIDDEN * KPAD; idx += gn * 256) {
        int c = idx / KPAD, k = idx - c * KPAD;
        w1t[idx] = (_Float16)((k < IN_DIM) ? W1[k * HIDDEN + c] : 0.f);
    }
    if (bid == gn - 1 && t < NBKT) bcnt[t] = 0;
    grid.sync();

    // phase 1: edge partition into bucket arena
    for (int c = bid; c < NCHUNK; c += gn) {
        part2_chunk<256>(c, t, sh.p.hist, sh.p.gbase, src, dst, bcnt, arena);
        __syncthreads();
    }
    grid.sync();

    // phase 2: per-bucket counting sort -> csr/rowstart/rowend/dinv
    for (int b = bid; b < NBKT; b += gn) {
        sort4_bucket<256>(b, t, sh.s.cnt, sh.s.cur, sh.s.wsum, arena, bcnt,
                          csr, rowstart, rowend, dinv);
        __syncthreads();
    }
    grid.sync();

    // phase 3: GEMM1 (MFMA)
    for (int tile = bid; tile < NTILE; tile += gn) {
        __syncthreads();                     // protect xs restage vs previous compute
        gemm1_tile(tile, t, sh.xs, x, w1t, dinv, h1s);
    }
    grid.sync();

    // phase 4: agg1 + bias + ReLU + W2
    for (int nb = bid * 4; nb < N_NODES; nb += gn * 4) {
        int node = nb + (t >> 6);
        if (node < N_NODES)
            agg1_node(node, lane, h1s, rowstart, rowend, csr, dinv, b1, W2, h2s);
    }
    grid.sync();

    // phase 5: agg2 -> out
    {
        int wid = t >> 6, sub = lane >> 4, el = lane & 15;
        for (int nb = bid * 16; nb < N_NODES; nb += gn * 16) {
            int node = nb + wid * 4 + sub;
            if (node < N_NODES)
                agg2_node(node, el, h2s, rowstart, rowend, csr, dinv, b2, outv);
        }
    }
}

// ================= fallback kernels (r5 pipeline, thin wrappers) ======================

__global__ __launch_bounds__(512) void k_part2(const int* __restrict__ src,
        const int* __restrict__ dst, int* __restrict__ bcnt, unsigned* __restrict__ arena) {
    __shared__ int hist[256];
    __shared__ int gbase[256];
    part2_chunk<512>(blockIdx.x, threadIdx.x, hist, gbase, src, dst, bcnt, arena);
}

__global__ __launch_bounds__(1024) void k_sort4(const unsigned* __restrict__ arena,
        const int* __restrict__ bcnt, int* __restrict__ csr, int* __restrict__ rowstart,
        int* __restrict__ rowend, float* __restrict__ dinv) {
    __shared__ int cnt[512];
    __shared__ int cur[512];
    __shared__ int wsum[4];
    sort4_bucket<1024>(blockIdx.x, threadIdx.x, cnt, cur, wsum, arena, bcnt,
                       csr, rowstart, rowend, dinv);
}

__global__ void k_w1t(const float* __restrict__ W1, _Float16* __restrict__ w1t) {
    int idx = blockIdx.x * 256 + threadIdx.x;
    if (idx < HIDDEN * KPAD) {
        int c = idx / KPAD, k = idx - c * KPAD;
        w1t[idx] = (_Float16)((k < IN_DIM) ? W1[k * HIDDEN + c] : 0.f);
    }
}

__global__ __launch_bounds__(256) void k_gemm1(const float* __restrict__ x,
        const _Float16* __restrict__ w1t, const float* __restrict__ dinv,
        _Float16* __restrict__ h1s) {
    __shared__ float xs[GROWS * IN_DIM];
    gemm1_tile(blockIdx.x, threadIdx.x, xs, x, w1t, dinv, h1s);
}

__global__ __launch_bounds__(256) void k_agg1(const _Float16* __restrict__ h1,
        const int* __restrict__ rowstart, const int* __restrict__ rowend,
        const int* __restrict__ csr, const float* __restrict__ dinv,
        const float* __restrict__ b1, const float* __restrict__ W2,
        float2* __restrict__ h2s) {
    int node = blockIdx.x * 4 + (threadIdx.x >> 6);
    agg1_node(node, threadIdx.x & 63, h1, rowstart, rowend, csr, dinv, b1, W2, h2s);
}

__global__ __launch_bounds__(256) void k_agg2(const float2* __restrict__ h2s,
        const int* __restrict__ rowstart, const int* __restrict__ rowend,
        const int* __restrict__ csr, const float* __restrict__ dinv,
        const float* __restrict__ b2, float2* __restrict__ out) {
    int wid = threadIdx.x >> 6, lane = threadIdx.x & 63;
    int node = blockIdx.x * 16 + wid * 4 + (lane >> 4);
    agg2_node(node, lane & 15, h2s, rowstart, rowend, csr, dinv, b2, out);
}

// ---------------- launch ----------------

extern "C" void kernel_launch(void* const* d_in, const int* in_sizes, int n_in,
                              void* d_out, int out_size, void* d_ws, size_t ws_size,
                              hipStream_t stream) {
    const float* x  = (const float*)d_in[0];
    const int*   ei = (const int*)d_in[1];
    const float* W1 = (const float*)d_in[2];
    const float* b1 = (const float*)d_in[3];
    const float* W2 = (const float*)d_in[4];
    const float* b2 = (const float*)d_in[5];
    float2* outv = (float2*)d_out;

    const int* src = ei;
    const int* dst = ei + N_EDGES;

    char* ws = (char*)d_ws;
    size_t off = 0;
    auto alloc = [&](size_t bytes) -> void* {
        void* p = ws + off;
        off += (bytes + 255) & ~(size_t)255;
        return p;
    };
    _Float16* h1s      = (_Float16*)alloc((size_t)N_NODES * HIDDEN * 2);  // 25.6 MB
    float*    dinv     = (float*)   alloc((size_t)N_NODES * 4);
    int*      rowstart = (int*)     alloc((size_t)N_NODES * 4);
    int*      rowend   = (int*)     alloc((size_t)N_NODES * 4);
    int*      bcnt     = (int*)     alloc((size_t)NBKT * 4);
    unsigned* arena    = (unsigned*)alloc((size_t)NBKT * PADCAP * 4);     // 8.0 MB
    int*      csr      = (int*)     alloc((size_t)NBKT * PADCAP * 4);     // 8.0 MB padded
    _Float16* w1t      = (_Float16*)alloc((size_t)HIDDEN * KPAD * 2);     // 45 KB
    float2*   h2s      = (float2*)  alloc((size_t)N_NODES * 8);

    static int coopBlocks = -2;     // -2 = not yet queried; 0 = disabled
    if (coopBlocks == -2) {
        int nb = 0;
        if (hipOccupancyMaxActiveBlocksPerMultiprocessor(&nb, k_mega, 256, 0) == hipSuccess
            && nb > 0)
            coopBlocks = nb;
        else
            coopBlocks = 0;
    }

    bool launched = false;
    if (coopBlocks > 0) {
        int gridn = coopBlocks * 256;           // 256 CUs on MI355X
        if (gridn > 768) gridn = 768;
        void* kargs[] = {(void*)&x, (void*)&src, (void*)&dst, (void*)&W1, (void*)&b1,
                         (void*)&W2, (void*)&b2, (void*)&h1s, (void*)&dinv,
                         (void*)&rowstart, (void*)&rowend, (void*)&bcnt, (void*)&arena,
                         (void*)&csr, (void*)&w1t, (void*)&h2s, (void*)&outv};
        hipError_t e = hipLaunchCooperativeKernel((const void*)k_mega, dim3(gridn),
                                                  dim3(256), kargs, 0, stream);
        if (e == hipSuccess) launched = true;
        else coopBlocks = 0;                    // disable for subsequent calls
    }

    if (!launched) {   // r5-proven fallback
        (void)hipMemsetAsync(bcnt, 0, (size_t)NBKT * 4, stream);
        k_w1t<<<(HIDDEN * KPAD + 255) / 256, 256, 0, stream>>>(W1, w1t);
        k_part2<<<NCHUNK, 512, 0, stream>>>(src, dst, bcnt, arena);
        k_sort4<<<NBKT, 1024, 0, stream>>>(arena, bcnt, csr, rowstart, rowend, dinv);
        k_gemm1<<<NTILE, 256, 0, stream>>>(x, w1t, dinv, h1s);
        k_agg1<<<N_NODES / 4, 256, 0, stream>>>(h1s, rowstart, rowend, csr, dinv, b1, W2, h2s);
        k_agg2<<<N_NODES / 16, 256, 0, stream>>>(h2s, rowstart, rowend, csr, dinv, b2, outv);
    }
}

// Round 8
// 248.420 us; speedup vs baseline: 2.5409x; 2.5409x over previous
//
#include <hip/hip_runtime.h>
#include <hip/hip_fp16.h>

#define N_NODES 100000
#define N_EDGES 1600000
#define IN_DIM  165
#define HIDDEN  128
#define OUT_DIM 2

#define NBKT 196        // ceil(100000/512) buckets of 512 nodes
#define CHUNK 4096      // edges per partition block
#define NCHUNK ((N_EDGES + CHUNK - 1) / CHUNK)   // 391
#define PADCAP 10240    // arena/csr slots per bucket (mean 8163, sigma ~90)
#define KPAD 176        // 5*32 + 16
#define GROWS 64        // x rows staged per gemm1 block

typedef _Float16 half8_t __attribute__((ext_vector_type(8)));
typedef _Float16 half4_t __attribute__((ext_vector_type(4)));
typedef float floatx4 __attribute__((ext_vector_type(4)));

// ---------------- phase 1: chunk hist -> claim -> direct scatter into padded arena ----
// entry = src | (dst&511)<<17  (26 bits)

__global__ __launch_bounds__(512) void k_part2(const int* __restrict__ src,
                                               const int* __restrict__ dst,
                                               int* __restrict__ bcnt,
                                               unsigned* __restrict__ arena) {
    __shared__ int hist[256];
    __shared__ int gbase[256];

    int t = threadIdx.x;
    int e0 = blockIdx.x * CHUNK;
    int nE = N_EDGES - e0; if (nE > CHUNK) nE = CHUNK;
    int n4 = nE >> 2;                       // N_EDGES % 4 == 0, so no scalar tail
    const int4* dst4 = (const int4*)(dst + e0);
    const int4* src4 = (const int4*)(src + e0);

    if (t < 256) hist[t] = 0;
    __syncthreads();

    for (int i = t; i < n4; i += 512) {
        int4 d = dst4[i];
        atomicAdd(&hist[d.x >> 9], 1);
        atomicAdd(&hist[d.y >> 9], 1);
        atomicAdd(&hist[d.z >> 9], 1);
        atomicAdd(&hist[d.w >> 9], 1);
    }
    __syncthreads();

    if (t < NBKT) gbase[t] = t * PADCAP + atomicAdd(&bcnt[t], hist[t]);
    if (t < 256) hist[t] = 0;   // reuse as rank counter
    __syncthreads();

    for (int i = t; i < n4; i += 512) {
        int4 d = dst4[i];
        int4 s = src4[i];
        #pragma unroll
        for (int j = 0; j < 4; j++) {
            int dd = (j == 0) ? d.x : (j == 1) ? d.y : (j == 2) ? d.z : d.w;
            int ss = (j == 0) ? s.x : (j == 1) ? s.y : (j == 2) ? s.z : s.w;
            int bk = dd >> 9;
            unsigned entry = (unsigned)ss | ((unsigned)(dd & 511) << 17);
            int idx = atomicAdd(&hist[bk], 1);
            arena[gbase[bk] + idx] = entry;
        }
    }
}

// ---------------- phase 2: per-bucket sort into PADDED csr; rowstart/rowend + dinv ------

__global__ __launch_bounds__(1024) void k_sort4(const unsigned* __restrict__ arena,
                                                const int* __restrict__ bcnt,
                                                int* __restrict__ csr,
                                                int* __restrict__ rowstart,
                                                int* __restrict__ rowend,
                                                float* __restrict__ dinv) {
    __shared__ int cnt[512];
    __shared__ int cur[512];
    __shared__ int wsum[4];
    int b = blockIdx.x;
    int n0 = b << 9;
    int t = threadIdx.x;
    int lane = t & 63, wid = t >> 6;
    int total = bcnt[b];
    int abase = b * PADCAP;        // PADCAP*4 bytes aligned -> int4-safe base
    int dbase = b * PADCAP;        // csr uses the same padded layout
    int nt4 = total >> 2;
    const uint4* arena4 = (const uint4*)(arena + abase);

    if (t < 512) cnt[t] = 0;
    __syncthreads();
    for (int p = t; p < nt4; p += 1024) {
        uint4 e = arena4[p];
        atomicAdd(&cnt[e.x >> 17], 1);
        atomicAdd(&cnt[e.y >> 17], 1);
        atomicAdd(&cnt[e.z >> 17], 1);
        atomicAdd(&cnt[e.w >> 17], 1);
    }
    {
        int p = (nt4 << 2) + t;
        if (p < total) atomicAdd(&cnt[arena[abase + p] >> 17], 1);
    }
    __syncthreads();

    // 512-entry exclusive scan using first 256 threads (thread t owns locals 2t, 2t+1)
    int c0 = 0, c1 = 0, s = 0, inc = 0;
    if (t < 256) {
        c0 = cnt[2 * t];
        c1 = cnt[2 * t + 1];
        s = c0 + c1;
        inc = s;
        #pragma unroll
        for (int off = 1; off < 64; off <<= 1) {
            int y = __shfl_up(inc, off);
            if (lane >= off) inc += y;
        }
        if (lane == 63) wsum[wid] = inc;
    }
    __syncthreads();
    if (t == 0) {
        int acc = 0;
        #pragma unroll
        for (int w = 0; w < 4; w++) { int tv = wsum[w]; wsum[w] = acc; acc += tv; }
    }
    __syncthreads();
    if (t < 256) {
        int base = dbase + wsum[wid] + (inc - s);
        cur[2 * t] = base;
        cur[2 * t + 1] = base + c0;
        int node0 = n0 + 2 * t;
        if (node0 < N_NODES) {
            rowstart[node0] = base;
            rowend[node0] = base + c0;
            dinv[node0] = rsqrtf((float)(c0 + 1));
        }
        if (node0 + 1 < N_NODES) {
            rowstart[node0 + 1] = base + c0;
            rowend[node0 + 1] = base + c0 + c1;
            dinv[node0 + 1] = rsqrtf((float)(c1 + 1));
        }
    }
    __syncthreads();

    for (int p = t; p < nt4; p += 1024) {
        uint4 e = arena4[p];
        #pragma unroll
        for (int j = 0; j < 4; j++) {
            unsigned entry = (j == 0) ? e.x : (j == 1) ? e.y : (j == 2) ? e.z : e.w;
            int local = (int)(entry >> 17);
            int sv = (int)(entry & 0x1FFFFu);
            int pos = atomicAdd(&cur[local], 1);
            csr[pos] = sv;
        }
    }
    {
        int p = (nt4 << 2) + t;
        if (p < total) {
            unsigned entry = arena[abase + p];
            int local = (int)(entry >> 17);
            int sv = (int)(entry & 0x1FFFFu);
            int pos = atomicAdd(&cur[local], 1);
            csr[pos] = sv;
        }
    }
}

// ---------------- W1 transpose to fp16 [col][KPAD]; block 0 also zeroes bcnt ----------

__global__ void k_w1t(const float* __restrict__ W1, _Float16* __restrict__ w1t,
                      int* __restrict__ bcnt) {
    if (blockIdx.x == 0 && threadIdx.x < NBKT) bcnt[threadIdx.x] = 0;
    int idx = blockIdx.x * 256 + threadIdx.x;
    if (idx < HIDDEN * KPAD) {
        int c = idx / KPAD, k = idx - c * KPAD;
        float v = (k < IN_DIM) ? W1[k * HIDDEN + c] : 0.f;
        w1t[idx] = (_Float16)v;
    }
}

// ---------------- GEMM1 (f16 MFMA): h1s = dinv * (x @ W1), fp16 row-major out ----------
// LDS-staged x rows (coalesced float4).

__global__ __launch_bounds__(256) void k_gemm1(const float* __restrict__ x,
                                               const _Float16* __restrict__ w1t,
                                               const float* __restrict__ dinv,
                                               _Float16* __restrict__ h1s) {
    __shared__ float xs[GROWS * IN_DIM];    // 42240 B
    int t = threadIdx.x;
    int wid = t >> 6, lane = t & 63;
    int row0 = blockIdx.x * GROWS;
    int nrows = N_NODES - row0; if (nrows > GROWS) nrows = GROWS;   // tail 32, %16==0
    int nflt = nrows * IN_DIM;

    // coalesced stage: region [row0*165, +nflt) is contiguous; base is 16B-aligned
    const float4* xb4 = (const float4*)(x + (size_t)row0 * IN_DIM);
    float4* xs4 = (float4*)xs;
    int n4 = nflt >> 2;
    for (int i = t; i < n4; i += 256) xs4[i] = xb4[i];
    for (int i = (n4 << 2) + t; i < nflt; i += 256) xs[i] = x[(size_t)row0 * IN_DIM + i];
    __syncthreads();

    int mrow = wid * 16;                    // wave's first row within block
    if (mrow >= nrows) return;              // after syncthreads: safe
    int m = lane & 15;
    int quad = lane >> 4;
    const float* xrow = xs + (mrow + m) * IN_DIM;
    int grow = row0 + mrow;                 // global first row of this wave

    floatx4 acc[8];
    #pragma unroll
    for (int i = 0; i < 8; i++) acc[i] = (floatx4)(0.f);

    #pragma unroll
    for (int kc = 0; kc < 5; kc++) {
        int kb = kc * 32 + quad * 8;       // max 152; +7 = 159 < 165 -> always in-row
        half8_t a;
        #pragma unroll
        for (int j = 0; j < 8; j++) a[j] = (_Float16)xrow[kb + j];
        #pragma unroll
        for (int cb = 0; cb < 8; cb++) {
            int col = cb * 16 + m;
            half8_t bf = *(const half8_t*)&w1t[col * KPAD + kb];
            acc[cb] = __builtin_amdgcn_mfma_f32_16x16x32_f16(a, bf, acc[cb], 0, 0, 0);
        }
    }
    // K tail: 160..164 via 16x16x16 (k = quad*4 + j) -- guarded LDS reads
    {
        int kb = 160 + quad * 4;
        half4_t a;
        #pragma unroll
        for (int j = 0; j < 4; j++)
            a[j] = (kb + j < IN_DIM) ? (_Float16)xrow[kb + j] : (_Float16)0.f;
        #pragma unroll
        for (int cb = 0; cb < 8; cb++) {
            int col = cb * 16 + m;
            half4_t bf = *(const half4_t*)&w1t[col * KPAD + kb];
            acc[cb] = __builtin_amdgcn_mfma_f32_16x16x16f16(a, bf, acc[cb], 0, 0, 0);
        }
    }
    // epilogue: scale by dinv[row], store fp16 (C/D: col=lane&15, row=quad*4+reg)
    float dv[4];
    #pragma unroll
    for (int r = 0; r < 4; r++) dv[r] = dinv[grow + quad * 4 + r];
    #pragma unroll
    for (int cb = 0; cb < 8; cb++) {
        #pragma unroll
        for (int r = 0; r < 4; r++) {
            h1s[(size_t)(grow + quad * 4 + r) * HIDDEN + cb * 16 + m] =
                (_Float16)(acc[cb][r] * dv[r]);
        }
    }
}

// ---------------- Fused agg1 + bias + ReLU + W2 (128->2) ----------------
// r2-proven structure; nodeoff allows split launches (diagnostic: expose #2 kernel
// in rocprof top-5 without perf cost -- agg1 is fill-rate-bound, grid still 12500).

__global__ __launch_bounds__(256) void k_agg1(const _Float16* __restrict__ h1,
                                              const int* __restrict__ rowstart,
                                              const int* __restrict__ rowend,
                                              const int* __restrict__ csr,
                                              const float* __restrict__ dinv,
                                              const float* __restrict__ b1,
                                              const float* __restrict__ W2,
                                              float2* __restrict__ h2s,
                                              int nodeoff) {
    int wid = threadIdx.x >> 6, lane = threadIdx.x & 63;
    int el = lane & 15;        // feature slot: owns features el*8 .. el*8+7
    int es = lane >> 4;        // edge slot 0..3
    int node = nodeoff + blockIdx.x * 4 + wid;

    float acc[8];
    // self term counted once (edge-slot 0)
    {
        half8_t v = *(const half8_t*)(h1 + (size_t)node * HIDDEN + el * 8);
        #pragma unroll
        for (int j = 0; j < 8; j++) acc[j] = (es == 0) ? (float)v[j] : 0.f;
    }

    int p0 = rowstart[node], p1 = rowend[node];
    int p = p0 + es;
    // 2-deep unroll: 2 gathers (2 KB/wave) in flight
    for (; p + 4 < p1; p += 8) {
        int sA = csr[p];
        int sB = csr[p + 4];
        half8_t vA = *(const half8_t*)(h1 + (size_t)sA * HIDDEN + el * 8);
        half8_t vB = *(const half8_t*)(h1 + (size_t)sB * HIDDEN + el * 8);
        #pragma unroll
        for (int j = 0; j < 8; j++) acc[j] += (float)vA[j];
        #pragma unroll
        for (int j = 0; j < 8; j++) acc[j] += (float)vB[j];
    }
    if (p < p1) {
        int s = csr[p];
        half8_t v = *(const half8_t*)(h1 + (size_t)s * HIDDEN + el * 8);
        #pragma unroll
        for (int j = 0; j < 8; j++) acc[j] += (float)v[j];
    }

    // reduce across the 4 edge slots (lanes el, el+16, el+32, el+48)
    #pragma unroll
    for (int j = 0; j < 8; j++) {
        acc[j] += __shfl_xor(acc[j], 16);
        acc[j] += __shfl_xor(acc[j], 32);
    }

    float di = dinv[node];
    // z = relu(di*acc + b1), then partial dot with W2 (128x2)
    float4 bb0 = ((const float4*)b1)[el * 2];
    float4 bb1 = ((const float4*)b1)[el * 2 + 1];
    float bv[8] = {bb0.x, bb0.y, bb0.z, bb0.w, bb1.x, bb1.y, bb1.z, bb1.w};
    float a0 = 0.f, a1 = 0.f;
    #pragma unroll
    for (int j = 0; j < 8; j++) {
        float z = fmaf(di, acc[j], bv[j]);
        float r = fmaxf(z, 0.f);
        float2 w = ((const float2*)W2)[el * 8 + j];
        a0 = fmaf(r, w.x, a0);
        a1 = fmaf(r, w.y, a1);
    }
    #pragma unroll
    for (int off = 8; off; off >>= 1) {
        a0 += __shfl_xor(a0, off);
        a1 += __shfl_xor(a1, off);
    }
    if (lane == 0) h2s[node] = make_float2(di * a0, di * a1);
}

// ---------------- agg2: out = b2 + dinv_i*(h2s_i + sum h2s_src) ----------------

__global__ __launch_bounds__(256) void k_agg2(const float2* __restrict__ h2s,
                                              const int* __restrict__ rowstart,
                                              const int* __restrict__ rowend,
                                              const int* __restrict__ csr,
                                              const float* __restrict__ dinv,
                                              const float* __restrict__ b2,
                                              float2* __restrict__ out) {
    int wid = threadIdx.x >> 6, lane = threadIdx.x & 63;
    int sub = lane >> 4, el = lane & 15;
    int node = blockIdx.x * 16 + wid * 4 + sub;   // grid 6250 * 16 = 100000 exactly
    int p0 = rowstart[node], p1 = rowend[node];
    float ax = 0.f, ay = 0.f;
    for (int p = p0 + el; p < p1; p += 16) {
        float2 g = h2s[csr[p]];
        ax += g.x;
        ay += g.y;
    }
    #pragma unroll
    for (int off = 8; off; off >>= 1) {
        ax += __shfl_xor(ax, off);
        ay += __shfl_xor(ay, off);
    }
    if (el == 0) {
        float2 self = h2s[node];
        float di = dinv[node];
        out[node] = make_float2(fmaf(di, self.x + ax, b2[0]),
                                fmaf(di, self.y + ay, b2[1]));
    }
}

// ---------------- launch ----------------

extern "C" void kernel_launch(void* const* d_in, const int* in_sizes, int n_in,
                              void* d_out, int out_size, void* d_ws, size_t ws_size,
                              hipStream_t stream) {
    const float* x  = (const float*)d_in[0];
    const int*   ei = (const int*)d_in[1];
    const float* W1 = (const float*)d_in[2];
    const float* b1 = (const float*)d_in[3];
    const float* W2 = (const float*)d_in[4];
    const float* b2 = (const float*)d_in[5];
    float* out = (float*)d_out;

    const int* src = ei;
    const int* dst = ei + N_EDGES;

    char* ws = (char*)d_ws;
    size_t off = 0;
    auto alloc = [&](size_t bytes) -> void* {
        void* p = ws + off;
        off += (bytes + 255) & ~(size_t)255;
        return p;
    };
    _Float16* h1s      = (_Float16*)alloc((size_t)N_NODES * HIDDEN * 2);  // 25.6 MB
    float*    dinv     = (float*)   alloc((size_t)N_NODES * 4);
    int*      rowstart = (int*)     alloc((size_t)N_NODES * 4);
    int*      rowend   = (int*)     alloc((size_t)N_NODES * 4);
    int*      bcnt     = (int*)     alloc((size_t)NBKT * 4);
    unsigned* arena    = (unsigned*)alloc((size_t)NBKT * PADCAP * 4);     // 8.0 MB
    int*      csr      = (int*)     alloc((size_t)NBKT * PADCAP * 4);     // 8.0 MB padded
    _Float16* w1t      = (_Float16*)alloc((size_t)HIDDEN * KPAD * 2);     // 45 KB
    float2*   h2s      = (float2*)  alloc((size_t)N_NODES * 8);

    k_w1t<<<(HIDDEN * KPAD + 255) / 256, 256, 0, stream>>>(W1, w1t, bcnt);
    k_part2<<<NCHUNK, 512, 0, stream>>>(src, dst, bcnt, arena);
    k_sort4<<<NBKT, 1024, 0, stream>>>(arena, bcnt, csr, rowstart, rowend, dinv);
    k_gemm1<<<(N_NODES + GROWS - 1) / GROWS, 256, 0, stream>>>(x, w1t, dinv, h1s);
    k_agg1<<<N_NODES / 8, 256, 0, stream>>>(h1s, rowstart, rowend, csr, dinv, b1, W2, h2s, 0);
    k_agg1<<<N_NODES / 8, 256, 0, stream>>>(h1s, rowstart, rowend, csr, dinv, b1, W2, h2s, N_NODES / 2);
    k_agg2<<<N_NODES / 16, 256, 0, stream>>>(h2s, rowstart, rowend, csr, dinv, b2, (float2*)out);
}

// Round 9
// 239.387 us; speedup vs baseline: 2.6368x; 1.0377x over previous
//
#include <hip/hip_runtime.h>
#include <hip/hip_fp16.h>

#define N_NODES 100000
#define N_EDGES 1600000
#define IN_DIM  165
#define HIDDEN  128
#define OUT_DIM 2

#define NBKT 196        // ceil(100000/512) buckets of 512 nodes
#define CHUNK 4096      // edges per partition block
#define NCHUNK ((N_EDGES + CHUNK - 1) / CHUNK)   // 391
#define PADCAP 10240    // arena/csr slots per bucket (mean 8163, sigma ~90)
#define KPAD 176        // 5*32 + 16
#define GROWS 64        // x rows staged per gemm1 block
#define XSTRIDE 176     // LDS row stride (halfs); pad 165..175 zeroed

typedef _Float16 half8_t __attribute__((ext_vector_type(8)));
typedef _Float16 half4_t __attribute__((ext_vector_type(4)));
typedef float floatx4 __attribute__((ext_vector_type(4)));

// ---------------- phase 1: chunk hist -> claim -> direct scatter into padded arena ----
// entry = src | (dst&511)<<17  (26 bits)

__global__ __launch_bounds__(512) void k_part2(const int* __restrict__ src,
                                               const int* __restrict__ dst,
                                               int* __restrict__ bcnt,
                                               unsigned* __restrict__ arena) {
    __shared__ int hist[256];
    __shared__ int gbase[256];

    int t = threadIdx.x;
    int e0 = blockIdx.x * CHUNK;
    int nE = N_EDGES - e0; if (nE > CHUNK) nE = CHUNK;
    int n4 = nE >> 2;                       // N_EDGES % 4 == 0, so no scalar tail
    const int4* dst4 = (const int4*)(dst + e0);
    const int4* src4 = (const int4*)(src + e0);

    if (t < 256) hist[t] = 0;
    __syncthreads();

    for (int i = t; i < n4; i += 512) {
        int4 d = dst4[i];
        atomicAdd(&hist[d.x >> 9], 1);
        atomicAdd(&hist[d.y >> 9], 1);
        atomicAdd(&hist[d.z >> 9], 1);
        atomicAdd(&hist[d.w >> 9], 1);
    }
    __syncthreads();

    if (t < NBKT) gbase[t] = t * PADCAP + atomicAdd(&bcnt[t], hist[t]);
    if (t < 256) hist[t] = 0;   // reuse as rank counter
    __syncthreads();

    for (int i = t; i < n4; i += 512) {
        int4 d = dst4[i];
        int4 s = src4[i];
        #pragma unroll
        for (int j = 0; j < 4; j++) {
            int dd = (j == 0) ? d.x : (j == 1) ? d.y : (j == 2) ? d.z : d.w;
            int ss = (j == 0) ? s.x : (j == 1) ? s.y : (j == 2) ? s.z : s.w;
            int bk = dd >> 9;
            unsigned entry = (unsigned)ss | ((unsigned)(dd & 511) << 17);
            int idx = atomicAdd(&hist[bk], 1);
            arena[gbase[bk] + idx] = entry;
        }
    }
}

// ---------------- phase 2: per-bucket sort into PADDED csr; rowstart/rowend + dinv ------

__global__ __launch_bounds__(1024) void k_sort4(const unsigned* __restrict__ arena,
                                                const int* __restrict__ bcnt,
                                                int* __restrict__ csr,
                                                int* __restrict__ rowstart,
                                                int* __restrict__ rowend,
                                                float* __restrict__ dinv) {
    __shared__ int cnt[512];
    __shared__ int cur[512];
    __shared__ int wsum[4];
    int b = blockIdx.x;
    int n0 = b << 9;
    int t = threadIdx.x;
    int lane = t & 63, wid = t >> 6;
    int total = bcnt[b];
    int abase = b * PADCAP;        // PADCAP*4 bytes aligned -> int4-safe base
    int dbase = b * PADCAP;        // csr uses the same padded layout
    int nt4 = total >> 2;
    const uint4* arena4 = (const uint4*)(arena + abase);

    if (t < 512) cnt[t] = 0;
    __syncthreads();
    for (int p = t; p < nt4; p += 1024) {
        uint4 e = arena4[p];
        atomicAdd(&cnt[e.x >> 17], 1);
        atomicAdd(&cnt[e.y >> 17], 1);
        atomicAdd(&cnt[e.z >> 17], 1);
        atomicAdd(&cnt[e.w >> 17], 1);
    }
    {
        int p = (nt4 << 2) + t;
        if (p < total) atomicAdd(&cnt[arena[abase + p] >> 17], 1);
    }
    __syncthreads();

    // 512-entry exclusive scan using first 256 threads (thread t owns locals 2t, 2t+1)
    int c0 = 0, c1 = 0, s = 0, inc = 0;
    if (t < 256) {
        c0 = cnt[2 * t];
        c1 = cnt[2 * t + 1];
        s = c0 + c1;
        inc = s;
        #pragma unroll
        for (int off = 1; off < 64; off <<= 1) {
            int y = __shfl_up(inc, off);
            if (lane >= off) inc += y;
        }
        if (lane == 63) wsum[wid] = inc;
    }
    __syncthreads();
    if (t == 0) {
        int acc = 0;
        #pragma unroll
        for (int w = 0; w < 4; w++) { int tv = wsum[w]; wsum[w] = acc; acc += tv; }
    }
    __syncthreads();
    if (t < 256) {
        int base = dbase + wsum[wid] + (inc - s);
        cur[2 * t] = base;
        cur[2 * t + 1] = base + c0;
        int node0 = n0 + 2 * t;
        if (node0 < N_NODES) {
            rowstart[node0] = base;
            rowend[node0] = base + c0;
            dinv[node0] = rsqrtf((float)(c0 + 1));
        }
        if (node0 + 1 < N_NODES) {
            rowstart[node0 + 1] = base + c0;
            rowend[node0 + 1] = base + c0 + c1;
            dinv[node0 + 1] = rsqrtf((float)(c1 + 1));
        }
    }
    __syncthreads();

    for (int p = t; p < nt4; p += 1024) {
        uint4 e = arena4[p];
        #pragma unroll
        for (int j = 0; j < 4; j++) {
            unsigned entry = (j == 0) ? e.x : (j == 1) ? e.y : (j == 2) ? e.z : e.w;
            int local = (int)(entry >> 17);
            int sv = (int)(entry & 0x1FFFFu);
            int pos = atomicAdd(&cur[local], 1);
            csr[pos] = sv;
        }
    }
    {
        int p = (nt4 << 2) + t;
        if (p < total) {
            unsigned entry = arena[abase + p];
            int local = (int)(entry >> 17);
            int sv = (int)(entry & 0x1FFFFu);
            int pos = atomicAdd(&cur[local], 1);
            csr[pos] = sv;
        }
    }
}

// ---------------- W1 transpose to fp16 [col][KPAD]; block 0 also zeroes bcnt ----------

__global__ void k_w1t(const float* __restrict__ W1, _Float16* __restrict__ w1t,
                      int* __restrict__ bcnt) {
    if (blockIdx.x == 0 && threadIdx.x < NBKT) bcnt[threadIdx.x] = 0;
    int idx = blockIdx.x * 256 + threadIdx.x;
    if (idx < HIDDEN * KPAD) {
        int c = idx / KPAD, k = idx - c * KPAD;
        float v = (k < IN_DIM) ? W1[k * HIDDEN + c] : 0.f;
        w1t[idx] = (_Float16)v;
    }
}

// ---------------- GEMM1 (f16 MFMA): h1s = dinv * (x @ W1), fp16 row-major out ----------
// v3: fp16 XOR-swizzled LDS x-tile (22.5 KB -> 7 blocks/CU vs 3 with fp32) and
// ds_read_b128 A-fragments (1 vector read per kc vs 8 scalar f32 + 8 cvt).
// Swizzle idx ^= ((row&7)<<3) makes lanes m,m+4 hit different 16B slots (was 4-way
// aliasing at 506K conflict cycles); residual m,m+8 pairing is 2-way = free.
// __launch_bounds__(256,8) targets <=64 VGPR so occupancy is LDS-bound (7 blocks).

__global__ __launch_bounds__(256, 8) void k_gemm1(const float* __restrict__ x,
                                                  const _Float16* __restrict__ w1t,
                                                  const float* __restrict__ dinv,
                                                  _Float16* __restrict__ h1s) {
    __shared__ __align__(16) _Float16 xs[GROWS * XSTRIDE];   // 22528 B
    int t = threadIdx.x;
    int wid = t >> 6, lane = t & 63;
    int row0 = blockIdx.x * GROWS;
    int nrows = N_NODES - row0; if (nrows > GROWS) nrows = GROWS;   // tail 32, %16==0
    int nflt = nrows * IN_DIM;                                      // always %4==0

    // stage: coalesced float4 global reads -> swizzled fp16 LDS writes
    const float4* xb4 = (const float4*)(x + (size_t)row0 * IN_DIM);
    int n4 = nflt >> 2;
    for (int i = t; i < n4; i += 256) {
        float4 v = xb4[i];
        int e = i << 2;
        #pragma unroll
        for (int j = 0; j < 4; j++) {
            int ee = e + j;
            int r = ee / IN_DIM;                 // magic-mul
            int c = ee - r * IN_DIM;
            float f = (j == 0) ? v.x : (j == 1) ? v.y : (j == 2) ? v.z : v.w;
            xs[(r * XSTRIDE + c) ^ ((r & 7) << 3)] = (_Float16)f;
        }
    }
    // zero-pad cols IN_DIM..XSTRIDE-1 (rows < nrows suffice; do all GROWS, cheap)
    for (int i = t; i < GROWS * (XSTRIDE - IN_DIM); i += 256) {
        int r = i / (XSTRIDE - IN_DIM);
        int c = IN_DIM + (i - r * (XSTRIDE - IN_DIM));
        xs[(r * XSTRIDE + c) ^ ((r & 7) << 3)] = (_Float16)0.f;
    }
    __syncthreads();

    int mrow = wid * 16;                    // wave's first row within block
    if (mrow >= nrows) return;              // after syncthreads: safe
    int m = lane & 15;
    int quad = lane >> 4;
    int rbase = (mrow + m) * XSTRIDE;
    int sm = (m & 7) << 3;                  // swizzle mask ((mrow+m)&7 == m&7)
    int grow = row0 + mrow;                 // global first row of this wave

    floatx4 acc[8];
    #pragma unroll
    for (int i = 0; i < 8; i++) acc[i] = (floatx4)(0.f);

    #pragma unroll
    for (int kc = 0; kc < 5; kc++) {
        int kb = kc * 32 + quad * 8;
        half8_t a = *(const half8_t*)&xs[(rbase + kb) ^ sm];
        #pragma unroll
        for (int cb = 0; cb < 8; cb++) {
            int col = cb * 16 + m;
            half8_t bf = *(const half8_t*)&w1t[col * KPAD + kb];
            acc[cb] = __builtin_amdgcn_mfma_f32_16x16x32_f16(a, bf, acc[cb], 0, 0, 0);
        }
    }
    // K tail: 160..175 via 16x16x16 (cols >=165 zero in BOTH xs pad and w1t pad)
    {
        int kb = 160 + quad * 4;
        half4_t a = *(const half4_t*)&xs[(rbase + kb) ^ sm];
        #pragma unroll
        for (int cb = 0; cb < 8; cb++) {
            int col = cb * 16 + m;
            half4_t bf = *(const half4_t*)&w1t[col * KPAD + kb];
            acc[cb] = __builtin_amdgcn_mfma_f32_16x16x16f16(a, bf, acc[cb], 0, 0, 0);
        }
    }
    // epilogue: scale by dinv[row], store fp16 (C/D: col=lane&15, row=quad*4+reg)
    float dv[4];
    #pragma unroll
    for (int r = 0; r < 4; r++) dv[r] = dinv[grow + quad * 4 + r];
    #pragma unroll
    for (int cb = 0; cb < 8; cb++) {
        #pragma unroll
        for (int r = 0; r < 4; r++) {
            h1s[(size_t)(grow + quad * 4 + r) * HIDDEN + cb * 16 + m] =
                (_Float16)(acc[cb][r] * dv[r]);
        }
    }
}

// ---------------- Fused agg1 + bias + ReLU + W2 (128->2) ----------------
// r2-proven structure: one wave per node, 16 feature-lanes x 4 edge-slots,
// 16B/lane half8 gathers, 2-deep pipeline, cached csr loads.

__global__ __launch_bounds__(256) void k_agg1(const _Float16* __restrict__ h1,
                                              const int* __restrict__ rowstart,
                                              const int* __restrict__ rowend,
                                              const int* __restrict__ csr,
                                              const float* __restrict__ dinv,
                                              const float* __restrict__ b1,
                                              const float* __restrict__ W2,
                                              float2* __restrict__ h2s,
                                              int nodeoff) {
    int wid = threadIdx.x >> 6, lane = threadIdx.x & 63;
    int el = lane & 15;        // feature slot: owns features el*8 .. el*8+7
    int es = lane >> 4;        // edge slot 0..3
    int node = nodeoff + blockIdx.x * 4 + wid;

    float acc[8];
    // self term counted once (edge-slot 0)
    {
        half8_t v = *(const half8_t*)(h1 + (size_t)node * HIDDEN + el * 8);
        #pragma unroll
        for (int j = 0; j < 8; j++) acc[j] = (es == 0) ? (float)v[j] : 0.f;
    }

    int p0 = rowstart[node], p1 = rowend[node];
    int p = p0 + es;
    // 2-deep unroll: 2 gathers (2 KB/wave) in flight
    for (; p + 4 < p1; p += 8) {
        int sA = csr[p];
        int sB = csr[p + 4];
        half8_t vA = *(const half8_t*)(h1 + (size_t)sA * HIDDEN + el * 8);
        half8_t vB = *(const half8_t*)(h1 + (size_t)sB * HIDDEN + el * 8);
        #pragma unroll
        for (int j = 0; j < 8; j++) acc[j] += (float)vA[j];
        #pragma unroll
        for (int j = 0; j < 8; j++) acc[j] += (float)vB[j];
    }
    if (p < p1) {
        int s = csr[p];
        half8_t v = *(const half8_t*)(h1 + (size_t)s * HIDDEN + el * 8);
        #pragma unroll
        for (int j = 0; j < 8; j++) acc[j] += (float)v[j];
    }

    // reduce across the 4 edge slots (lanes el, el+16, el+32, el+48)
    #pragma unroll
    for (int j = 0; j < 8; j++) {
        acc[j] += __shfl_xor(acc[j], 16);
        acc[j] += __shfl_xor(acc[j], 32);
    }

    float di = dinv[node];
    // z = relu(di*acc + b1), then partial dot with W2 (128x2)
    float4 bb0 = ((const float4*)b1)[el * 2];
    float4 bb1 = ((const float4*)b1)[el * 2 + 1];
    float bv[8] = {bb0.x, bb0.y, bb0.z, bb0.w, bb1.x, bb1.y, bb1.z, bb1.w};
    float a0 = 0.f, a1 = 0.f;
    #pragma unroll
    for (int j = 0; j < 8; j++) {
        float z = fmaf(di, acc[j], bv[j]);
        float r = fmaxf(z, 0.f);
        float2 w = ((const float2*)W2)[el * 8 + j];
        a0 = fmaf(r, w.x, a0);
        a1 = fmaf(r, w.y, a1);
    }
    #pragma unroll
    for (int off = 8; off; off >>= 1) {
        a0 += __shfl_xor(a0, off);
        a1 += __shfl_xor(a1, off);
    }
    if (lane == 0) h2s[node] = make_float2(di * a0, di * a1);
}

// ---------------- agg2: out = b2 + dinv_i*(h2s_i + sum h2s_src) ----------------

__global__ __launch_bounds__(256) void k_agg2(const float2* __restrict__ h2s,
                                              const int* __restrict__ rowstart,
                                              const int* __restrict__ rowend,
                                              const int* __restrict__ csr,
                                              const float* __restrict__ dinv,
                                              const float* __restrict__ b2,
                                              float2* __restrict__ out) {
    int wid = threadIdx.x >> 6, lane = threadIdx.x & 63;
    int sub = lane >> 4, el = lane & 15;
    int node = blockIdx.x * 16 + wid * 4 + sub;   // grid 6250 * 16 = 100000 exactly
    int p0 = rowstart[node], p1 = rowend[node];
    float ax = 0.f, ay = 0.f;
    for (int p = p0 + el; p < p1; p += 16) {
        float2 g = h2s[csr[p]];
        ax += g.x;
        ay += g.y;
    }
    #pragma unroll
    for (int off = 8; off; off >>= 1) {
        ax += __shfl_xor(ax, off);
        ay += __shfl_xor(ay, off);
    }
    if (el == 0) {
        float2 self = h2s[node];
        float di = dinv[node];
        out[node] = make_float2(fmaf(di, self.x + ax, b2[0]),
                                fmaf(di, self.y + ay, b2[1]));
    }
}

// ---------------- launch ----------------

extern "C" void kernel_launch(void* const* d_in, const int* in_sizes, int n_in,
                              void* d_out, int out_size, void* d_ws, size_t ws_size,
                              hipStream_t stream) {
    const float* x  = (const float*)d_in[0];
    const int*   ei = (const int*)d_in[1];
    const float* W1 = (const float*)d_in[2];
    const float* b1 = (const float*)d_in[3];
    const float* W2 = (const float*)d_in[4];
    const float* b2 = (const float*)d_in[5];
    float* out = (float*)d_out;

    const int* src = ei;
    const int* dst = ei + N_EDGES;

    char* ws = (char*)d_ws;
    size_t off = 0;
    auto alloc = [&](size_t bytes) -> void* {
        void* p = ws + off;
        off += (bytes + 255) & ~(size_t)255;
        return p;
    };
    _Float16* h1s      = (_Float16*)alloc((size_t)N_NODES * HIDDEN * 2);  // 25.6 MB
    float*    dinv     = (float*)   alloc((size_t)N_NODES * 4);
    int*      rowstart = (int*)     alloc((size_t)N_NODES * 4);
    int*      rowend   = (int*)     alloc((size_t)N_NODES * 4);
    int*      bcnt     = (int*)     alloc((size_t)NBKT * 4);
    unsigned* arena    = (unsigned*)alloc((size_t)NBKT * PADCAP * 4);     // 8.0 MB
    int*      csr      = (int*)     alloc((size_t)NBKT * PADCAP * 4);     // 8.0 MB padded
    _Float16* w1t      = (_Float16*)alloc((size_t)HIDDEN * KPAD * 2);     // 45 KB
    float2*   h2s      = (float2*)  alloc((size_t)N_NODES * 8);

    k_w1t<<<(HIDDEN * KPAD + 255) / 256, 256, 0, stream>>>(W1, w1t, bcnt);
    k_part2<<<NCHUNK, 512, 0, stream>>>(src, dst, bcnt, arena);
    k_sort4<<<NBKT, 1024, 0, stream>>>(arena, bcnt, csr, rowstart, rowend, dinv);
    k_gemm1<<<(N_NODES + GROWS - 1) / GROWS, 256, 0, stream>>>(x, w1t, dinv, h1s);
    k_agg1<<<N_NODES / 4, 256, 0, stream>>>(h1s, rowstart, rowend, csr, dinv, b1, W2, h2s, 0);
    k_agg2<<<N_NODES / 16, 256, 0, stream>>>(h2s, rowstart, rowend, csr, dinv, b2, (float2*)out);
}